// Round 5
// baseline (125.483 us; speedup 1.0000x reference)
//
#include <hip/hip_runtime.h>

#define HW   112
#define KK   576

typedef __attribute__((ext_vector_type(8))) short s16x8;
typedef __attribute__((ext_vector_type(4))) float f32x4;
typedef __attribute__((ext_vector_type(2))) float f32x2;

// LDS A-tile geometry: [cc 2][plane 3][row 10][px 18][granule 4 x 16B], row +32B pad
// so the stage ds_write pattern is 2-way (free) and reads spread banks.
#define LP_ROW   1184
#define LP_PHASE (10 * LP_ROW)            // 11,840 B per plane; 35,520 B per cc-half
#define SWZ(px)  (((px) & 3) ^ (((px) >> 2) & 3))

__device__ inline unsigned short f2bf(float f) {
    unsigned u = __float_as_uint(f);
    u += 0x7FFF + ((u >> 16) & 1);            // RNE
    return (unsigned short)(u >> 16);
}
// single-instruction packed f32->bf16 (RNE, bit-identical to f2bf on finite inputs)
__device__ inline unsigned pack2(float lo, float hi) {
    unsigned r;
    asm("v_cvt_pk_bf16_f32 %0, %1, %2" : "=v"(r) : "v"(lo), "v"(hi));
    return r;
}

// ---- tiny prep: weight transpose + row sums ----
// Wb flat index: (((tap*2 + cc)*4 + nt)*64 + lane)*8 + j
//   k = cc*32 + (lane>>4)*8 + j, n = nt*16 + (lane&15), value = W[n][k*9 + tap]
__global__ __launch_bounds__(256) void prep_w(const float* __restrict__ W,
                                              unsigned short* __restrict__ wb,
                                              float* __restrict__ S) {
    const int bid = blockIdx.x, t = threadIdx.x;
    if (bid < 144) {                         // weight transpose: 36,864 elements
        const int i   = bid * 256 + t;
        const int j   = i & 7;
        const int l   = (i >> 3) & 63;
        const int nt  = (i >> 9) & 3;
        const int cc  = (i >> 11) & 1;
        const int tap = i >> 12;
        const int c   = cc * 32 + ((l >> 4) << 3) + j;
        const int o   = nt * 16 + (l & 15);
        wb[i] = f2bf(W[o * KK + c * 9 + tap]);
    } else {                                 // row sums
        __shared__ float partial[256];
        const int o = t >> 2, part = t & 3;
        const float4* row = (const float4*)(W + o * KK) + part * 36;
        float s = 0.f;
        for (int k = 0; k < 36; ++k) { float4 v = row[k]; s += v.x + v.y + v.z + v.w; }
        partial[t] = s;
        __syncthreads();
        if (part == 0) S[o] = partial[t] + partial[t + 1] + partial[t + 2] + partial[t + 3];
    }
}

// ---- fused conv, merged oc halves: 512 thr / 8 waves per block ----
// Wave wv: wvr = wv&3 owns rows 2wvr,2wvr+1; oc2 = wv>>2 owns a 32-oc half.
// ONE stage (320 threads, units = (cc 2, cp 16, srow 10)) fills BOTH cc buffers in
// the prologue -- stage work, img loads, and ds_writes are done once per spatial
// tile instead of once per oc-half (the r4 kernel staged every tile twice).
// Single barrier; cc1's B fragments reload after cc0 compute (register dep only).
__global__ __launch_bounds__(512, 4) void conv_fused(const float* __restrict__ img,
                                                     const unsigned short* __restrict__ wb,
                                                     const float* __restrict__ S,
                                                     float* __restrict__ out) {
    __shared__ __align__(16) char tile[2][3 * LP_PHASE];   // 71,040 B -> 2 blocks/CU

    const int t = threadIdx.x, wv = t >> 6, lane = t & 63;
    const int wvr = wv & 3, oc2 = wv >> 2;
    const int m = lane & 15, q = lane >> 4;

    const int bid = blockIdx.x;       // 784: b = bid&7 (XCD pin)
    const int b = bid & 7;
    const int r = bid >> 3;           // 0..97 = 14 ty * 7 tx
    const int ty = r / 7, tx = r - ty * 7;
    const int y0 = ty * 8, x0 = tx * 16;

    f32x4 acc[3][2][2];               // [power][at][ntl]
    #pragma unroll
    for (int p = 0; p < 3; ++p)
        #pragma unroll
        for (int at = 0; at < 2; ++at)
            #pragma unroll
            for (int ntl = 0; ntl < 2; ++ntl)
                acc[p][at][ntl] = (f32x4){0.f, 0.f, 0.f, 0.f};

    const char* wbase = (const char*)wb + oc2 * 2048 + lane * 16;
    s16x8 bfr[9][2];                  // current cc's B fragments in registers

    auto loadW = [&](int cc) {
        #pragma unroll
        for (int tap = 0; tap < 9; ++tap)
            #pragma unroll
            for (int ntl = 0; ntl < 2; ++ntl)
                bfr[tap][ntl] = *(const s16x8*)(wbase + (tap * 2 + cc) * 4096 + ntl * 1024);
    };

    // ---- prologue stage: both cc halves, once per block ----
    {
        const int scc  = (t >= 160) ? 1 : 0;
        const int su   = t - scc * 160;
        const int cp   = su & 15, srow = su >> 4;
        const int sy   = y0 + srow - 1;           // img row (halo)
        if (t < 320) {
            float va[2][18];
            if (sy < 0 || sy >= HW) {
                #pragma unroll
                for (int e = 0; e < 2; ++e)
                    #pragma unroll
                    for (int px = 0; px < 18; ++px) va[e][px] = 0.f;
            } else {
                #pragma unroll
                for (int e = 0; e < 2; ++e) {
                    const float* rp = img + ((size_t)(b * 64 + scc * 32 + cp * 2 + e) * HW + sy) * HW;
                    va[e][0] = (x0 > 0) ? rp[x0 - 1] : 0.f;
                    #pragma unroll
                    for (int i2 = 0; i2 < 4; ++i2) {
                        const float4 v = *(const float4*)(rp + x0 + i2 * 4);
                        va[e][1 + 4 * i2] = v.x;
                        va[e][2 + 4 * i2] = v.y;
                        va[e][3 + 4 * i2] = v.z;
                        va[e][4 + 4 * i2] = v.w;
                    }
                    va[e][17] = (x0 + 16 < HW) ? rp[x0 + 16] : 0.f;
                }
            }
            char* wp = tile[scc] + srow * LP_ROW + (cp & 3) * 4;
            #pragma unroll
            for (int px = 0; px < 18; ++px) {
                char* a0 = wp + px * 64 + (((cp >> 2) ^ SWZ(px)) << 4);
                const float l1 = va[0][px], h1 = va[1][px];
                const float l2 = l1 * l1,   h2 = h1 * h1;
                const float l3 = l2 * l1,   h3 = h2 * h1;
                *(unsigned*)(a0)                = pack2(l1, h1);
                *(unsigned*)(a0 + LP_PHASE)     = pack2(l2, h2);
                *(unsigned*)(a0 + 2 * LP_PHASE) = pack2(l3, h3);
            }
        }
    }
    loadW(0);                          // after pack: va/bfr liveness disjoint
    __syncthreads();                   // both buffers ready

    auto compute_plane = [&](const char* bufbase, int p) {   // p compile-time at call sites
        const char* base = bufbase + p * LP_PHASE;
        #pragma unroll
        for (int kx = 0; kx < 3; ++kx) {
            const int pxr  = m + kx;
            const int c8sr = q ^ SWZ(pxr);
            const int abase = wvr * (2 * LP_ROW) + pxr * 64 + c8sr * 16;
            s16x8 af[4];
            #pragma unroll
            for (int r4 = 0; r4 < 4; ++r4)
                af[r4] = *(const s16x8*)&base[abase + r4 * LP_ROW];
            __builtin_amdgcn_s_setprio(1);
            #pragma unroll
            for (int ky = 0; ky < 3; ++ky)
                #pragma unroll
                for (int at = 0; at < 2; ++at)
                    #pragma unroll
                    for (int ntl = 0; ntl < 2; ++ntl)
                        acc[p][at][ntl] = __builtin_amdgcn_mfma_f32_16x16x32_bf16(
                            af[at + ky], bfr[ky * 3 + kx][ntl], acc[p][at][ntl], 0, 0, 0);
            __builtin_amdgcn_s_setprio(0);
        }
    };

    compute_plane(tile[0], 0);
    compute_plane(tile[0], 1);
    compute_plane(tile[0], 2);
    loadW(1);                          // register dep orders this after cc0 MFMAs
    compute_plane(tile[1], 0);
    compute_plane(tile[1], 1);
    compute_plane(tile[1], 2);

    // ---- epilogue: telescoped diffs, f32x2 packed; D: n = lane&15, px = q*4+reg ----
    #pragma unroll
    for (int ntl = 0; ntl < 2; ++ntl) {
        const int o = (oc2 * 2 + ntl) * 16 + (lane & 15);
        const float Sv = S[o];
        const float fS = -0.000287f / 75.f * Sv;
        const float cg1 = 0.8448f  + 0.001309f * Sv;
        const float D1  = 0.52992f - 0.003809f * Sv;
        const float D2  = 0.45312f + 0.001546f * Sv;
        const float D3  = 1.152f   - 0.006386f * Sv;
        const float D4  = 0.91392f - 0.00283f  * Sv;
        #pragma unroll
        for (int at = 0; at < 2; ++at) {
            float res[4];
            #pragma unroll
            for (int h = 0; h < 2; ++h) {
                const f32x2 u1 = {acc[0][at][ntl][2 * h], acc[0][at][ntl][2 * h + 1]};
                const f32x2 u2 = {acc[1][at][ntl][2 * h], acc[1][at][ntl][2 * h + 1]};
                const f32x2 u3 = {acc[2][at][ntl][2 * h], acc[2][at][ntl][2 * h + 1]};
                const f32x2 f  = fS   + 0.00354667f * u1 - 0.00146267f * u2;
                const f32x2 g1 = cg1  + 0.00619f    * u1 - 0.009f      * u2 + 0.001383f * u3;
                const f32x2 d1 = D1   - 0.00316f    * u1 + 0.00416f    * u2 + 0.016117f * u3;
                const f32x2 d2 = D2   - 0.00116f    * u1 + 0.006717f   * u2 - 0.00248f  * u3;
                const f32x2 d3 = D3   - 0.000753f   * u1 + 0.005643f   * u2 - 0.00602f  * u3;
                const f32x2 d4 = D4   - 0.000691f   * u1 + 0.00085f    * u2 - 0.00487f  * u3;
                f32x2 E;
                E.x = __expf(-10.f * f.x);
                E.y = __expf(-10.f * f.y);
                const f32x2 den1 = 1.f + E * 4.4816890703f;
                const f32x2 den2 = 1.f + E * 9.9741824548f;
                const f32x2 den3 = 1.f + E * 24.5325301971f;
                const f32x2 den4 = 1.f + E * 49.4024491055f;
                f32x2 o2 = g1;
                o2.x += __builtin_amdgcn_rcpf(den1.x) * d1.x + __builtin_amdgcn_rcpf(den2.x) * d2.x
                      + __builtin_amdgcn_rcpf(den3.x) * d3.x + __builtin_amdgcn_rcpf(den4.x) * d4.x;
                o2.y += __builtin_amdgcn_rcpf(den1.y) * d1.y + __builtin_amdgcn_rcpf(den2.y) * d2.y
                      + __builtin_amdgcn_rcpf(den3.y) * d3.y + __builtin_amdgcn_rcpf(den4.y) * d4.y;
                res[2 * h] = o2.x; res[2 * h + 1] = o2.y;
            }
            const int y = y0 + 2 * wvr + at;
            float* op = out + (((size_t)(b * 64 + o)) * HW + y) * HW + x0 + q * 4;
            *(float4*)op = make_float4(res[0], res[1], res[2], res[3]);
        }
    }
}

extern "C" void kernel_launch(void* const* d_in, const int* in_sizes, int n_in,
                              void* d_out, int out_size, void* d_ws, size_t ws_size,
                              hipStream_t stream) {
    const float* img = (const float*)d_in[0];
    const float* w   = (const float*)d_in[1];
    float* outp = (float*)d_out;
    unsigned short* wb = (unsigned short*)d_ws;          // 36,864 shorts
    float* S = (float*)(wb + 36864);                     // 64 floats

    hipLaunchKernelGGL(prep_w,     dim3(145), dim3(256), 0, stream, w, wb, S);
    hipLaunchKernelGGL(conv_fused, dim3(784), dim3(512), 0, stream, img, wb, S, outp);
}

// Round 6
// 108.846 us; speedup vs baseline: 1.1528x; 1.1528x over previous
//
#include <hip/hip_runtime.h>

#define HW   112
#define KK   576

typedef __attribute__((ext_vector_type(8))) short s16x8;
typedef __attribute__((ext_vector_type(4))) float f32x4;
typedef __attribute__((ext_vector_type(2))) float f32x2;

// LDS A-tile geometry: [cc 2][plane 3][row 10][px 18][granule 4 x 16B], row +32B pad
// so the stage ds_write pattern is 2-way (free) and reads spread banks.
#define LP_ROW   1184
#define LP_PHASE (10 * LP_ROW)            // 11,840 B per plane; 35,520 B per cc-half
#define SWZ(px)  (((px) & 3) ^ (((px) >> 2) & 3))

__device__ inline unsigned short f2bf(float f) {
    unsigned u = __float_as_uint(f);
    u += 0x7FFF + ((u >> 16) & 1);            // RNE
    return (unsigned short)(u >> 16);
}
// single-instruction packed f32->bf16 (RNE, bit-identical to f2bf on finite inputs)
__device__ inline unsigned pack2(float lo, float hi) {
    unsigned r;
    asm("v_cvt_pk_bf16_f32 %0, %1, %2" : "=v"(r) : "v"(lo), "v"(hi));
    return r;
}

// ---- tiny prep: weight transpose + row sums ----
// Wb flat index: (((tap*2 + cc)*4 + nt)*64 + lane)*8 + j
//   k = cc*32 + (lane>>4)*8 + j, n = nt*16 + (lane&15), value = W[n][k*9 + tap]
__global__ __launch_bounds__(256) void prep_w(const float* __restrict__ W,
                                              unsigned short* __restrict__ wb,
                                              float* __restrict__ S) {
    const int bid = blockIdx.x, t = threadIdx.x;
    if (bid < 144) {                         // weight transpose: 36,864 elements
        const int i   = bid * 256 + t;
        const int j   = i & 7;
        const int l   = (i >> 3) & 63;
        const int nt  = (i >> 9) & 3;
        const int cc  = (i >> 11) & 1;
        const int tap = i >> 12;
        const int c   = cc * 32 + ((l >> 4) << 3) + j;
        const int o   = nt * 16 + (l & 15);
        wb[i] = f2bf(W[o * KK + c * 9 + tap]);
    } else {                                 // row sums
        __shared__ float partial[256];
        const int o = t >> 2, part = t & 3;
        const float4* row = (const float4*)(W + o * KK) + part * 36;
        float s = 0.f;
        for (int k = 0; k < 36; ++k) { float4 v = row[k]; s += v.x + v.y + v.z + v.w; }
        partial[t] = s;
        __syncthreads();
        if (part == 0) S[o] = partial[t] + partial[t + 1] + partial[t + 2] + partial[t + 3];
    }
}

// ---- fused conv, merged oc halves: 512 thr / 8 waves per block ----
// Wave wv: wvr = wv&3 owns rows 2wvr,2wvr+1; oc2 = wv>>2 owns a 32-oc half.
// ONE stage (320 threads, units = (cc 2, cp 16, srow 10)) fills BOTH cc buffers in
// the prologue -- stage work, img loads, and ds_writes are done once per spatial
// tile instead of once per oc-half.
// Round-5 lesson: __launch_bounds__(512,4) clamped VGPR to 64 -> 81 MB of scratch
// spill (WRITE_SIZE 3.2x). (512,2) caps at 256; natural allocation ~100 stays
// <=128 so HW still co-resides 2 blocks/CU (16 waves).
__global__ __launch_bounds__(512, 2) void conv_fused(const float* __restrict__ img,
                                                     const unsigned short* __restrict__ wb,
                                                     const float* __restrict__ S,
                                                     float* __restrict__ out) {
    __shared__ __align__(16) char tile[2][3 * LP_PHASE];   // 71,040 B -> 2 blocks/CU

    const int t = threadIdx.x, wv = t >> 6, lane = t & 63;
    const int wvr = wv & 3, oc2 = wv >> 2;
    const int m = lane & 15, q = lane >> 4;

    const int bid = blockIdx.x;       // 784: b = bid&7 (XCD pin)
    const int b = bid & 7;
    const int r = bid >> 3;           // 0..97 = 14 ty * 7 tx
    const int ty = r / 7, tx = r - ty * 7;
    const int y0 = ty * 8, x0 = tx * 16;

    f32x4 acc[3][2][2];               // [power][at][ntl]
    #pragma unroll
    for (int p = 0; p < 3; ++p)
        #pragma unroll
        for (int at = 0; at < 2; ++at)
            #pragma unroll
            for (int ntl = 0; ntl < 2; ++ntl)
                acc[p][at][ntl] = (f32x4){0.f, 0.f, 0.f, 0.f};

    const char* wbase = (const char*)wb + oc2 * 2048 + lane * 16;
    s16x8 bfr[9][2];                  // current cc's B fragments in registers

    auto loadW = [&](int cc) {
        #pragma unroll
        for (int tap = 0; tap < 9; ++tap)
            #pragma unroll
            for (int ntl = 0; ntl < 2; ++ntl)
                bfr[tap][ntl] = *(const s16x8*)(wbase + (tap * 2 + cc) * 4096 + ntl * 1024);
    };

    // ---- prologue stage: both cc halves, once per block ----
    {
        const int scc  = (t >= 160) ? 1 : 0;
        const int su   = t - scc * 160;
        const int cp   = su & 15, srow = su >> 4;
        const int sy   = y0 + srow - 1;           // img row (halo)
        if (t < 320) {
            float va[2][18];
            if (sy < 0 || sy >= HW) {
                #pragma unroll
                for (int e = 0; e < 2; ++e)
                    #pragma unroll
                    for (int px = 0; px < 18; ++px) va[e][px] = 0.f;
            } else {
                #pragma unroll
                for (int e = 0; e < 2; ++e) {
                    const float* rp = img + ((size_t)(b * 64 + scc * 32 + cp * 2 + e) * HW + sy) * HW;
                    va[e][0] = (x0 > 0) ? rp[x0 - 1] : 0.f;
                    #pragma unroll
                    for (int i2 = 0; i2 < 4; ++i2) {
                        const float4 v = *(const float4*)(rp + x0 + i2 * 4);
                        va[e][1 + 4 * i2] = v.x;
                        va[e][2 + 4 * i2] = v.y;
                        va[e][3 + 4 * i2] = v.z;
                        va[e][4 + 4 * i2] = v.w;
                    }
                    va[e][17] = (x0 + 16 < HW) ? rp[x0 + 16] : 0.f;
                }
            }
            char* wp = tile[scc] + srow * LP_ROW + (cp & 3) * 4;
            #pragma unroll
            for (int px = 0; px < 18; ++px) {
                char* a0 = wp + px * 64 + (((cp >> 2) ^ SWZ(px)) << 4);
                const float l1 = va[0][px], h1 = va[1][px];
                const float l2 = l1 * l1,   h2 = h1 * h1;
                const float l3 = l2 * l1,   h3 = h2 * h1;
                *(unsigned*)(a0)                = pack2(l1, h1);
                *(unsigned*)(a0 + LP_PHASE)     = pack2(l2, h2);
                *(unsigned*)(a0 + 2 * LP_PHASE) = pack2(l3, h3);
            }
        }
    }
    loadW(0);                          // after pack: va/bfr liveness disjoint
    __syncthreads();                   // both buffers ready

    auto compute_plane = [&](const char* bufbase, int p) {   // p compile-time at call sites
        const char* base = bufbase + p * LP_PHASE;
        #pragma unroll
        for (int kx = 0; kx < 3; ++kx) {
            const int pxr  = m + kx;
            const int c8sr = q ^ SWZ(pxr);
            const int abase = wvr * (2 * LP_ROW) + pxr * 64 + c8sr * 16;
            s16x8 af[4];
            #pragma unroll
            for (int r4 = 0; r4 < 4; ++r4)
                af[r4] = *(const s16x8*)&base[abase + r4 * LP_ROW];
            __builtin_amdgcn_s_setprio(1);
            #pragma unroll
            for (int ky = 0; ky < 3; ++ky)
                #pragma unroll
                for (int at = 0; at < 2; ++at)
                    #pragma unroll
                    for (int ntl = 0; ntl < 2; ++ntl)
                        acc[p][at][ntl] = __builtin_amdgcn_mfma_f32_16x16x32_bf16(
                            af[at + ky], bfr[ky * 3 + kx][ntl], acc[p][at][ntl], 0, 0, 0);
            __builtin_amdgcn_s_setprio(0);
        }
    };

    compute_plane(tile[0], 0);
    compute_plane(tile[0], 1);
    compute_plane(tile[0], 2);
    loadW(1);                          // register dep orders this after cc0 MFMAs
    compute_plane(tile[1], 0);
    compute_plane(tile[1], 1);
    compute_plane(tile[1], 2);

    // ---- epilogue: telescoped diffs, f32x2 packed; D: n = lane&15, px = q*4+reg ----
    #pragma unroll
    for (int ntl = 0; ntl < 2; ++ntl) {
        const int o = (oc2 * 2 + ntl) * 16 + (lane & 15);
        const float Sv = S[o];
        const float fS = -0.000287f / 75.f * Sv;
        const float cg1 = 0.8448f  + 0.001309f * Sv;
        const float D1  = 0.52992f - 0.003809f * Sv;
        const float D2  = 0.45312f + 0.001546f * Sv;
        const float D3  = 1.152f   - 0.006386f * Sv;
        const float D4  = 0.91392f - 0.00283f  * Sv;
        #pragma unroll
        for (int at = 0; at < 2; ++at) {
            float res[4];
            #pragma unroll
            for (int h = 0; h < 2; ++h) {
                const f32x2 u1 = {acc[0][at][ntl][2 * h], acc[0][at][ntl][2 * h + 1]};
                const f32x2 u2 = {acc[1][at][ntl][2 * h], acc[1][at][ntl][2 * h + 1]};
                const f32x2 u3 = {acc[2][at][ntl][2 * h], acc[2][at][ntl][2 * h + 1]};
                const f32x2 f  = fS   + 0.00354667f * u1 - 0.00146267f * u2;
                const f32x2 g1 = cg1  + 0.00619f    * u1 - 0.009f      * u2 + 0.001383f * u3;
                const f32x2 d1 = D1   - 0.00316f    * u1 + 0.00416f    * u2 + 0.016117f * u3;
                const f32x2 d2 = D2   - 0.00116f    * u1 + 0.006717f   * u2 - 0.00248f  * u3;
                const f32x2 d3 = D3   - 0.000753f   * u1 + 0.005643f   * u2 - 0.00602f  * u3;
                const f32x2 d4 = D4   - 0.000691f   * u1 + 0.00085f    * u2 - 0.00487f  * u3;
                f32x2 E;
                E.x = __expf(-10.f * f.x);
                E.y = __expf(-10.f * f.y);
                const f32x2 den1 = 1.f + E * 4.4816890703f;
                const f32x2 den2 = 1.f + E * 9.9741824548f;
                const f32x2 den3 = 1.f + E * 24.5325301971f;
                const f32x2 den4 = 1.f + E * 49.4024491055f;
                f32x2 o2 = g1;
                o2.x += __builtin_amdgcn_rcpf(den1.x) * d1.x + __builtin_amdgcn_rcpf(den2.x) * d2.x
                      + __builtin_amdgcn_rcpf(den3.x) * d3.x + __builtin_amdgcn_rcpf(den4.x) * d4.x;
                o2.y += __builtin_amdgcn_rcpf(den1.y) * d1.y + __builtin_amdgcn_rcpf(den2.y) * d2.y
                      + __builtin_amdgcn_rcpf(den3.y) * d3.y + __builtin_amdgcn_rcpf(den4.y) * d4.y;
                res[2 * h] = o2.x; res[2 * h + 1] = o2.y;
            }
            const int y = y0 + 2 * wvr + at;
            float* op = out + (((size_t)(b * 64 + o)) * HW + y) * HW + x0 + q * 4;
            *(float4*)op = make_float4(res[0], res[1], res[2], res[3]);
        }
    }
}

extern "C" void kernel_launch(void* const* d_in, const int* in_sizes, int n_in,
                              void* d_out, int out_size, void* d_ws, size_t ws_size,
                              hipStream_t stream) {
    const float* img = (const float*)d_in[0];
    const float* w   = (const float*)d_in[1];
    float* outp = (float*)d_out;
    unsigned short* wb = (unsigned short*)d_ws;          // 36,864 shorts
    float* S = (float*)(wb + 36864);                     // 64 floats

    hipLaunchKernelGGL(prep_w,     dim3(145), dim3(256), 0, stream, w, wb, S);
    hipLaunchKernelGGL(conv_fused, dim3(784), dim3(512), 0, stream, img, wb, S, outp);
}